// Round 7
// baseline (274.597 us; speedup 1.0000x reference)
//
#include <hip/hip_runtime.h>
#include <hip/hip_bf16.h>
#include <stdint.h>

#define TSTEPS 500
#define BB 32
#define N0 512
#define N1 1024
#define N2 512

typedef unsigned short ushort_t;
typedef __attribute__((ext_vector_type(8))) short short8;
typedef __attribute__((ext_vector_type(4))) float f32x4;

// ---------------- bf16 helpers --------------------------------------------
__device__ __forceinline__ ushort_t f2b(float x) {
    union { float f; uint32_t u; } c; c.f = x;
    uint32_t r = (c.u + 0x7fffu + ((c.u >> 16) & 1u)) >> 16;
    return (ushort_t)r;
}
__device__ __forceinline__ float b2f(ushort_t u) {
    union { uint32_t u; float f; } c; c.u = ((uint32_t)u) << 16;
    return c.f;
}

// ---------------- GLIFR step, algebraically reduced ------------------------
// Returns sigma = sigmoid((v-10)/10) == s*DT (SPIKE_R*DT == 1); the 20 is
// folded into the weight planes and the final store.
__device__ __forceinline__ float glifr_step(float& v, float& a0, float& a1,
                                            float x) {
    const float INV_I0 = 1.0f / 700.0f;
    const float C2 = 9.43f / 700.0f;            // DT*K_M = 1/(R*I0)
    const float CE = 0.14426950408889634f;      // 0.1*log2(e)
    const float CE10 = 1.4426950408889634f;     // 1.0*log2(e)
    const float C0 = 1.0f - 0.05f * 0.003f;
    const float C1 = 1.0f - 0.05f * 0.1f;
    const float AMP0 = -9.18f, AMP1 = -198.94f;

    float asum = a0 + a1;
    float drv = fmaf(asum, INV_I0, x);
    float e = exp2f(fmaf(v, -CE, CE10));            // exp((10-v)*0.1)
    float sig = __builtin_amdgcn_rcpf(1.0f + e);    // sigmoid
    float na0 = fmaf(sig, a0 + AMP0, a0 * C0);
    float na1 = fmaf(sig, a1 + AMP1, a1 * C1);
    float nv = fmaf(-sig, v, fmaf(-C2, v, v + drv));
    a0 = na0; a1 = na1; v = nv;
    return sig;
}

// ---------------- scan body: f32 drive in, packed(hi|lo<<16) or f32 out ----
// MODE 0: drive at t.  MODE 1: drive at t-1 (0 at t=0).  MODE 2: drive at
// t-1, f32 out scaled by SPIKE_R=20 (final layer).
#define PD 25
template <int NW, int MODE>
__device__ __forceinline__ void scan_body(const float* __restrict__ drive,
                                          uint32_t* __restrict__ pout,
                                          float* __restrict__ fout, int idx) {
    const int S = BB * NW;

    auto LD = [&](int t) -> float {
        if (MODE == 0) return drive[(size_t)t * S + idx];
        return (t == 0) ? 0.0f : drive[(size_t)(t - 1) * S + idx];
    };

    float v = 0.f, a0 = 0.f, a1 = 0.f;

    auto STEP = [&](int t, float x) {
        float sig = glifr_step(v, a0, a1, x);
        size_t o = (size_t)t * S + idx;
        if (MODE == 2) {
            fout[o] = 20.0f * sig;
        } else {
            ushort_t hi = f2b(sig);
            float lo = sig - b2f(hi);
            pout[o] = (uint32_t)hi | ((uint32_t)f2b(lo) << 16);
        }
    };

    float p[PD];
#pragma unroll
    for (int i = 0; i < PD; ++i) p[i] = LD(i);

    for (int t = 0; t < TSTEPS - PD; t += PD) {
        float q[PD];
#pragma unroll
        for (int i = 0; i < PD; ++i) q[i] = LD(t + PD + i);
#pragma unroll
        for (int i = 0; i < PD; ++i) STEP(t + i, p[i]);
#pragma unroll
        for (int i = 0; i < PD; ++i) p[i] = q[i];
    }
#pragma unroll
    for (int i = 0; i < PD; ++i) STEP(TSTEPS - PD + i, p[i]);
}

// ---------------- scan0 fused with weight split ----------------------------
__global__ void scan0_wsplit(const float* __restrict__ inputs,
                             uint32_t* __restrict__ s0,
                             const float* __restrict__ W1,
                             const float* __restrict__ W2,
                             ushort_t* __restrict__ w1h, ushort_t* __restrict__ w1l,
                             ushort_t* __restrict__ w2h, ushort_t* __restrict__ w2l) {
    const int bid = blockIdx.x;
    if (bid < (BB * N0) / 64) {
        scan_body<N0, 0>(inputs, s0, nullptr, bid * 64 + threadIdx.x);
    } else {
        int i = (bid - (BB * N0) / 64) * 64 + threadIdx.x;  // 0..524287
        float a = 20.0f * W1[i];
        ushort_t h = f2b(a);
        w1h[i] = h; w1l[i] = f2b(a - b2f(h));
        float b = 20.0f * W2[i];
        h = f2b(b);
        w2h[i] = h; w2l[i] = f2b(b - b2f(h));
    }
}

template <int NW>
__global__ void scan_mid(const float* __restrict__ drive,
                         uint32_t* __restrict__ sout) {
    scan_body<NW, 1>(drive, sout, nullptr,
                     blockIdx.x * blockDim.x + threadIdx.x);
}

__global__ void scan_last(const float* __restrict__ drive,
                          float* __restrict__ out) {
    scan_body<N2, 2>(drive, nullptr, out,
                     blockIdx.x * blockDim.x + threadIdx.x);
}

// ---------------- bf16x3-split MFMA GEMM -----------------------------------
// C[M,N] = A[M,K]*B[N,K]^T. A packed (hi|lo<<16) loaded DIRECTLY from global
// into MFMA fragments (two dwordx4 per fragment, v_perm unpack in regs) —
// no LDS for A. B pre-split bf16 planes staged via global_load_lds into a
// double-buffered 32KB LDS (waves 2,3), XOR-swizzled. One barrier per K-tile.
template <int NBY, int KC>
__global__ __launch_bounds__(256, 2) void gemm_x3(
    const uint32_t* __restrict__ Apk,
    const ushort_t* __restrict__ Bh, const ushort_t* __restrict__ Bl,
    float* __restrict__ C) {
    constexpr int NC = NBY * 128;  // output row stride (columns)
    __shared__ char lds[32768];    // 2 bufs x {Bh 8KB | Bl 8KB}
    const int tid = threadIdx.x;
    const int lane = tid & 63, wave = tid >> 6;

    // bijective XCD swizzle (m204)
    const int id = blockIdx.x, nwg = gridDim.x;
    const int qq = nwg >> 3, rr = nwg & 7;
    const int xcd = id & 7, jj = id >> 3;
    const int wg = (xcd < rr ? xcd * (qq + 1) : rr * (qq + 1) + (xcd - rr) * qq) + jj;
    const int m0 = (wg / NBY) * 128;
    const int n0 = (wg % NBY) * 128;

    // B staging (waves 2,3): pre-swizzled global source, linear LDS dest
    const ushort_t* gB = (wave == 2) ? Bh : Bl;
    const int chunk_sw = (lane & 3) ^ ((lane >> 3) & 3);
    const size_t rowbB = (size_t)KC * 2;
    const char* gsrcB = (const char*)gB +
                        (size_t)(n0 + (lane >> 2)) * rowbB + (size_t)chunk_sw * 16;

    const int wm = wave >> 1, wn = wave & 1;
    const int r4 = lane & 15, kg = lane >> 4;
    const int slot = kg ^ ((r4 >> 1) & 3);
    const int fB = (wn * 64 + r4) * 64 + slot * 16;

    // A fragment base: row = m0 + wm*64 + i*16 + r4, k = ks*32 + kg*8 (+0..7)
    const uint32_t* aFrag = Apk + (size_t)(m0 + wm * 64 + r4) * KC + kg * 8;

    const int KSTEPS = KC / 32;

    f32x4 acc[4][4];
#pragma unroll
    for (int i = 0; i < 4; ++i)
#pragma unroll
        for (int j = 0; j < 4; ++j) acc[i][j] = (f32x4){0.f, 0.f, 0.f, 0.f};

    auto issueB = [&](int ks, int base) {
#pragma unroll
        for (int i = 0; i < 8; ++i) {
            __builtin_amdgcn_global_load_lds(
                (const __attribute__((address_space(1))) uint32_t*)(
                    gsrcB + (size_t)i * 16 * rowbB + (size_t)ks * 64),
                (__attribute__((address_space(3))) uint32_t*)(
                    lds + base + (wave - 2) * 8192 + i * 1024),
                16, 0, 0);
        }
    };
    auto loadA = [&](int ks, uint4* pk) {
#pragma unroll
        for (int i = 0; i < 4; ++i) {
            pk[2 * i] = *reinterpret_cast<const uint4*>(
                aFrag + (size_t)i * 16 * KC + ks * 32);
            pk[2 * i + 1] = *reinterpret_cast<const uint4*>(
                aFrag + (size_t)i * 16 * KC + ks * 32 + 4);
        }
    };
    auto compute = [&](const uint4* pk, int base) {
        short8 bh[4], bl[4];
#pragma unroll
        for (int j = 0; j < 4; ++j) {
            bh[j] = *(const short8*)(lds + base + fB + j * 1024);
            bl[j] = *(const short8*)(lds + base + 8192 + fB + j * 1024);
        }
#pragma unroll
        for (int i = 0; i < 4; ++i) {
            const uint4 p0 = pk[2 * i], p1 = pk[2 * i + 1];
            uint32_t h[4], l[4];
            h[0] = __builtin_amdgcn_perm(p0.y, p0.x, 0x05040100u);
            h[1] = __builtin_amdgcn_perm(p0.w, p0.z, 0x05040100u);
            h[2] = __builtin_amdgcn_perm(p1.y, p1.x, 0x05040100u);
            h[3] = __builtin_amdgcn_perm(p1.w, p1.z, 0x05040100u);
            l[0] = __builtin_amdgcn_perm(p0.y, p0.x, 0x07060302u);
            l[1] = __builtin_amdgcn_perm(p0.w, p0.z, 0x07060302u);
            l[2] = __builtin_amdgcn_perm(p1.y, p1.x, 0x07060302u);
            l[3] = __builtin_amdgcn_perm(p1.w, p1.z, 0x07060302u);
            short8 ah, al;
            uint32_t* ahp = reinterpret_cast<uint32_t*>(&ah);
            uint32_t* alp = reinterpret_cast<uint32_t*>(&al);
            ahp[0] = h[0]; ahp[1] = h[1]; ahp[2] = h[2]; ahp[3] = h[3];
            alp[0] = l[0]; alp[1] = l[1]; alp[2] = l[2]; alp[3] = l[3];
#pragma unroll
            for (int j = 0; j < 4; ++j) {
                acc[i][j] = __builtin_amdgcn_mfma_f32_16x16x32_bf16(
                    ah, bh[j], acc[i][j], 0, 0, 0);
                acc[i][j] = __builtin_amdgcn_mfma_f32_16x16x32_bf16(
                    ah, bl[j], acc[i][j], 0, 0, 0);
                acc[i][j] = __builtin_amdgcn_mfma_f32_16x16x32_bf16(
                    al, bh[j], acc[i][j], 0, 0, 0);
            }
        }
    };

    uint4 pk[8], pkN[8];
    // prologue: B tile 0 -> buf0, A tile 0 -> regs
    if (wave >= 2) issueB(0, 0);
    loadA(0, pk);
    __syncthreads();

    for (int ks = 0; ks < KSTEPS; ks += 2) {
        // phase A: compute tile ks from buf0; prefetch tile ks+1
        if (wave >= 2) issueB(ks + 1, 16384);
        loadA(ks + 1, pkN);
        compute(pk, 0);
        __syncthreads();
        // phase B: compute tile ks+1 from buf1; prefetch tile ks+2
        const bool more = (ks + 2 < KSTEPS);
        if (more) {
            if (wave >= 2) issueB(ks + 2, 0);
            loadA(ks + 2, pk);
        }
        compute(pkN, 16384);
        __syncthreads();
    }

    // epilogue: C/D layout col=lane&15, row=(lane>>4)*4+reg
#pragma unroll
    for (int i = 0; i < 4; ++i)
#pragma unroll
        for (int j = 0; j < 4; ++j)
#pragma unroll
            for (int r = 0; r < 4; ++r) {
                int row = m0 + wm * 64 + i * 16 + kg * 4 + r;
                int col = n0 + wn * 64 + j * 16 + r4;
                C[(size_t)row * NC + col] = acc[i][j][r];
            }
}

extern "C" void kernel_launch(void* const* d_in, const int* in_sizes, int n_in,
                              void* d_out, int out_size, void* d_ws,
                              size_t ws_size, hipStream_t stream) {
    const float* inputs = (const float*)d_in[0];  // [500,32,512]
    const float* W1 = (const float*)d_in[1];      // [1024,512]
    const float* W2 = (const float*)d_in[2];      // [512,1024]
    float* out = (float*)d_out;                   // [500,32,512]
    char* ws = (char*)d_ws;

    // workspace (bytes):
    //  region A [0, 65,536,000): s0 packed u32 (32.77MB); later s1 packed (65.54MB)
    //  region B [65,536,000, 131,072,000): x1 f32 (65.54MB); later x2 f32
    //  weights  [131,072,000, 135,266,304): w1h w1l w2h w2l (1MB each)
    uint32_t* s0 = (uint32_t*)ws;
    uint32_t* s1 = (uint32_t*)ws;             // s0 dead after gemm1
    float*    x1 = (float*)(ws + 65536000);
    float*    x2 = (float*)(ws + 65536000);   // x1 dead after scan1
    ushort_t* w1h = (ushort_t*)(ws + 131072000);
    ushort_t* w1l = (ushort_t*)(ws + 132120576);
    ushort_t* w2h = (ushort_t*)(ws + 133169152);
    ushort_t* w2l = (ushort_t*)(ws + 134217728);

    // 1) layer-0 recurrence -> packed sigma, fused with weight split
    scan0_wsplit<<<256 + 8192, 64, 0, stream>>>(inputs, s0, W1, W2,
                                                w1h, w1l, w2h, w2l);
    // 2) X1 = S0 @ (20*W1)^T -> f32 [16000,1024]
    gemm_x3<8, N0><<<1000, 256, 0, stream>>>(s0, w1h, w1l, x1);
    // 3) layer-1 recurrence -> packed sigma
    scan_mid<N1><<<512, 64, 0, stream>>>(x1, s1);
    // 4) X2 = S1 @ (20*W2)^T -> f32 [16000,512]
    gemm_x3<4, N1><<<500, 256, 0, stream>>>(s1, w2h, w2l, x2);
    // 5) layer-2 recurrence -> spikes (20*sigma) -> out
    scan_last<<<256, 64, 0, stream>>>(x2, out);
}